// Round 16
// baseline (117.626 us; speedup 1.0000x reference)
//
#include <hip/hip_runtime.h>
#include <stdint.h>

#define D_MODEL 1024
#define N_HEADS 16
#define D_K     64
#define T_SEQ   2048
#define BATCH   2
#define M_TOT   (BATCH * T_SEQ)   // 4096
#define QCH     128               // q rows per chunk (16 chunks per bh)

typedef __attribute__((ext_vector_type(8))) short  short8;
typedef __attribute__((ext_vector_type(4))) float  f32x4;
typedef __attribute__((ext_vector_type(4))) unsigned short u16x4;

typedef __attribute__((address_space(1))) void gvoid;
typedef __attribute__((address_space(3))) void lvoid;

// log2(e)/8 : folds the 1/sqrt(Dk) scale AND the exp->exp2 conversion into Q
#define QSCALE 0.18033688011112042f

static __device__ __forceinline__ unsigned short f2bf(float f) {
    union { float f; unsigned u; } v; v.f = f;
    unsigned u = v.u;
    u += 0x7fffu + ((u >> 16) & 1u);   // RNE
    return (unsigned short)(u >> 16);
}
static __device__ __forceinline__ float bf2f(unsigned short s) {
    union { unsigned u; float f; } v; v.u = ((unsigned)s) << 16;
    return v.f;
}
static __device__ __forceinline__ float fexp2(float x) {
    float r;
    asm("v_exp_f32 %0, %1" : "=v"(r) : "v"(x));
    return r;
}
static __device__ __forceinline__ unsigned cvt_pk_bf16(float lo, float hi) {
    unsigned r;
    asm("v_cvt_pk_bf16_f32 %0, %1, %2" : "=v"(r) : "v"(lo), "v"(hi));
    return r;
}

// ------- fused converter (proven R11-R15): z=0 -> x fp32->bf16,
// z=1..4 -> W fp32 [K][N] -> bf16 [N][K] transpose -------
__global__ void cvt_all(const float* __restrict__ x, unsigned short* __restrict__ xo,
                        const float* w0, const float* w1, const float* w2, const float* w3,
                        unsigned short* o0, unsigned short* o1, unsigned short* o2, unsigned short* o3) {
    if (blockIdx.z == 0) {
        const int tid = threadIdx.y * 32 + threadIdx.x;
        const int bid = blockIdx.y * 32 + blockIdx.x;          // 0..1023
        const float4* in4 = (const float4*)x;
        #pragma unroll
        for (int j = 0; j < 4; ++j) {
            int i = bid * 256 + tid + j * 262144;
            float4 v = in4[i];
            u16x4 o;
            o.x = f2bf(v.x); o.y = f2bf(v.y); o.z = f2bf(v.z); o.w = f2bf(v.w);
            *(u16x4*)&xo[(size_t)i * 4] = o;
        }
        return;
    }
    const float* w; unsigned short* o;
    switch (blockIdx.z - 1) {
        case 0: w = w0; o = o0; break;
        case 1: w = w1; o = o1; break;
        case 2: w = w2; o = o2; break;
        default: w = w3; o = o3; break;
    }
    __shared__ float tile[32][33];
    int n0 = blockIdx.x * 32, k0 = blockIdx.y * 32;
    int tx = threadIdx.x, ty = threadIdx.y;              // 32 x 8
    #pragma unroll
    for (int r = 0; r < 32; r += 8)
        tile[ty + r][tx] = w[(size_t)(k0 + ty + r) * D_MODEL + n0 + tx];
    __syncthreads();
    #pragma unroll
    for (int r = 0; r < 32; r += 8)
        o[(size_t)(n0 + ty + r) * D_MODEL + k0 + tx] = f2bf(tile[tx][ty + r]);
}

// ---------------- fused QKV 128x128-tile bf16 GEMM: 3-buffer counted-vmcnt ----------
// Staging addresses, fragment reads, MFMA order, and epilogue are BYTE-EXACT
// R9/R13 (every epilogue/staging perturbation regressed: R5/R7/R10-R12).
// ONLY change: K-loop is a 3-deep rolling pipeline (T4, m218): iter t stages
// tile t+2, computes tile t%3, then vmcnt(4) -- tile t+1 guaranteed landed,
// tile t+2's 4 loads stay in flight across the barrier (no vmcnt(0) drain).
__global__ __launch_bounds__(256) void gemm_qkv(const unsigned short* __restrict__ A,
                                                const unsigned short* __restrict__ wq,
                                                const unsigned short* __restrict__ wk,
                                                const unsigned short* __restrict__ wv,
                                                const float* __restrict__ bq,
                                                const float* __restrict__ bk,
                                                const float* __restrict__ bv,
                                                unsigned short* __restrict__ qo,
                                                unsigned short* __restrict__ ko,
                                                unsigned short* __restrict__ vo) {
    const int z = blockIdx.z;
    const unsigned short* Bt = (z == 0) ? wq : (z == 1) ? wk : wv;
    const float* bias = (z == 0) ? bq : (z == 1) ? bk : bv;
    const float alpha = (z == 0) ? QSCALE : 1.0f;

    __shared__ unsigned short lA[3][128 * 32];   // 24 KB
    __shared__ unsigned short lB[3][128 * 32];   // 24 KB
    const int tid  = threadIdx.x;
    const int w    = tid >> 6, lane = tid & 63;
    const int tm   = blockIdx.y, tn = blockIdx.x;
    const int wm   = w & 1, wn = w >> 1;
    const int i16  = lane & 15, g4 = lane >> 4;
    f32x4 acc[4][4] = {};

    const int rA0 = tm * 128, rB0 = tn * 128;
    const int srow = lane >> 2;
    const int skc  = (lane & 3) * 8;

    auto stage = [&](int buf, int k0) {          // 4 VMEM loads per thread, fixed order
        #pragma unroll
        for (int is = 0; is < 2; ++is) {
            int c   = is * 4 + w;
            int row = c * 16 + srow;
            __builtin_amdgcn_global_load_lds(
                (gvoid*)(A + (size_t)(rA0 + row) * D_MODEL + k0 + skc),
                (lvoid*)&lA[buf][c * 512], 16, 0, 0);
            __builtin_amdgcn_global_load_lds(
                (gvoid*)(Bt + (size_t)(rB0 + row) * D_MODEL + k0 + skc),
                (lvoid*)&lB[buf][c * 512], 16, 0, 0);
        }
    };

    stage(0, 0);
    stage(1, 32);
    asm volatile("s_waitcnt vmcnt(4)" ::: "memory");   // tile 0 landed; tile 1 may fly
    __builtin_amdgcn_s_barrier();
    __builtin_amdgcn_sched_barrier(0);

    for (int t = 0; t < 32; ++t) {
        const bool pre = (t + 2 < 32);
        if (pre) stage((t + 2) % 3, (t + 2) * 32);     // prefetch 2 tiles ahead

        const unsigned short* cA = &lA[t % 3][0];
        const unsigned short* cB = &lB[t % 3][0];
        short8 af[4], bfr[4];
        #pragma unroll
        for (int mi = 0; mi < 4; ++mi)
            af[mi] = *(const short8*)&cA[(wm * 64 + mi * 16 + i16) * 32 + g4 * 8];
        #pragma unroll
        for (int ni = 0; ni < 4; ++ni)
            bfr[ni] = *(const short8*)&cB[(wn * 64 + ni * 16 + i16) * 32 + g4 * 8];
        #pragma unroll
        for (int mi = 0; mi < 4; ++mi)
            #pragma unroll
            for (int ni = 0; ni < 4; ++ni)
                acc[mi][ni] = __builtin_amdgcn_mfma_f32_16x16x32_bf16(af[mi], bfr[ni], acc[mi][ni], 0, 0, 0);

        // counted sync: tile t+1 guaranteed resident; tile t+2's loads stay in flight
        if (pre) asm volatile("s_waitcnt vmcnt(4)" ::: "memory");
        else     asm volatile("s_waitcnt vmcnt(0)" ::: "memory");
        __builtin_amdgcn_s_barrier();
        __builtin_amdgcn_sched_barrier(0);
    }

    #pragma unroll
    for (int mi = 0; mi < 4; ++mi)
        #pragma unroll
        for (int ni = 0; ni < 4; ++ni) {
            int col = tn * 128 + wn * 64 + ni * 16 + i16;
            float bv2 = bias[col];
            #pragma unroll
            for (int r = 0; r < 4; ++r) {
                int row = tm * 128 + wm * 64 + mi * 16 + g4 * 4 + r;
                float val = (acc[mi][ni][r] + bv2) * alpha;
                int b = row >> 11, t = row & (T_SEQ - 1);
                int h = col >> 6,  d = col & (D_K - 1);
                unsigned short bfv = f2bf(val);
                if (z == 2)
                    vo[(((size_t)(b * N_HEADS + h)) * D_K + d) * T_SEQ + t] = bfv;
                else if (z == 1)
                    ko[(((size_t)(b * N_HEADS + h)) * T_SEQ + t) * D_K + d] = bfv;
                else
                    qo[(((size_t)(b * N_HEADS + h)) * T_SEQ + t) * D_K + d] = bfv;
            }
        }
}

// ---------------- output-projection GEMM (fp32 out + bias), 128x64 tiles ----------
// Proven R14/R15: dim3(16,32) = 512 blocks = 2/CU.
__global__ __launch_bounds__(256) void gemm_out(const unsigned short* __restrict__ A,
                                                const unsigned short* __restrict__ Bt,
                                                const float* __restrict__ bias,
                                                float* __restrict__ Cout) {
    __shared__ unsigned short lA[128 * 32];   // 8 KB
    __shared__ unsigned short lB[64 * 32];    // 4 KB
    const int tid  = threadIdx.x;
    const int w    = tid >> 6, lane = tid & 63;
    const int tm   = blockIdx.y, tn = blockIdx.x;      // tn: 0..15 (64-wide)
    const int wm   = w & 1, wn = w >> 1;               // wn: 0..1 (32-wide)
    const int i16  = lane & 15, g4 = lane >> 4;
    f32x4 acc[4][2] = {};

    const int rA0 = tm * 128, rB0 = tn * 64;
    const int srow = lane >> 2;
    const int skc  = (lane & 3) * 8;

    for (int k0 = 0; k0 < D_MODEL; k0 += 32) {
        #pragma unroll
        for (int is = 0; is < 2; ++is) {
            int c   = is * 4 + w;                      // A: 8 chunks of 16 rows
            int row = c * 16 + srow;
            __builtin_amdgcn_global_load_lds(
                (gvoid*)(A + (size_t)(rA0 + row) * D_MODEL + k0 + skc),
                (lvoid*)&lA[c * 512], 16, 0, 0);
        }
        {
            int row = w * 16 + srow;                   // B: 4 chunks of 16 rows
            __builtin_amdgcn_global_load_lds(
                (gvoid*)(Bt + (size_t)(rB0 + row) * D_MODEL + k0 + skc),
                (lvoid*)&lB[w * 512], 16, 0, 0);
        }
        __syncthreads();
        short8 af[4], bfr[2];
        #pragma unroll
        for (int mi = 0; mi < 4; ++mi)
            af[mi] = *(const short8*)&lA[(wm * 64 + mi * 16 + i16) * 32 + g4 * 8];
        #pragma unroll
        for (int ni = 0; ni < 2; ++ni)
            bfr[ni] = *(const short8*)&lB[(wn * 32 + ni * 16 + i16) * 32 + g4 * 8];
        #pragma unroll
        for (int mi = 0; mi < 4; ++mi)
            #pragma unroll
            for (int ni = 0; ni < 2; ++ni)
                acc[mi][ni] = __builtin_amdgcn_mfma_f32_16x16x32_bf16(af[mi], bfr[ni], acc[mi][ni], 0, 0, 0);
        __syncthreads();
    }

    #pragma unroll
    for (int mi = 0; mi < 4; ++mi)
        #pragma unroll
        for (int ni = 0; ni < 2; ++ni) {
            int col = tn * 64 + wn * 32 + ni * 16 + i16;
            float bv2 = bias[col];
            #pragma unroll
            for (int r = 0; r < 4; ++r) {
                int row = tm * 128 + wm * 64 + mi * 16 + g4 * 4 + r;
                Cout[(size_t)row * D_MODEL + col] = acc[mi][ni][r] + bv2;
            }
        }
}

// ---------------- causal flash attention v7 -- BYTE-EXACT R13/R15 ----------------
// 768 blocks x 256 thr (4 waves), paired chunks, 3-way kv split, 48KB LDS ->
// 3 blocks/CU all resident. DO NOT un-pair (R14 regressed).
__global__ __launch_bounds__(256, 3) void flash7(const unsigned short* __restrict__ q,
                                                 const unsigned short* __restrict__ k,
                                                 const unsigned short* __restrict__ vt,
                                                 unsigned short* __restrict__ op01,
                                                 unsigned short* __restrict__ op2,
                                                 float* __restrict__ lws) {
    __shared__ unsigned short lK[2][64 * 64];    // 16 KB  [kv row][d]
    __shared__ unsigned short lV[2][64 * 64];    // 16 KB  [d][kv col]
    __shared__ unsigned short lP[4][2][16 * 64]; // 16 KB  per-wave, per-qt P slab
    const int tid  = threadIdx.x;
    const int w    = tid >> 6, lane = tid & 63;
    const int i16  = lane & 15, g4 = lane >> 4;
    const int l8   = lane & 7,  g8 = lane >> 3;
    const int nb   = blockIdx.x;                 // bh*24 + s*8 + p
    const int p    = nb & 7;
    const int s    = (nb >> 3) % 3;
    const int bh   = nb / 24;

    const unsigned short* kp = k  + (size_t)bh * T_SEQ * D_K;
    const unsigned short* vp = vt + (size_t)bh * D_K * T_SEQ;
    const int swz  = (i16 & 7) << 3;             // XOR swizzle (element units)
    const int csrc = (l8 ^ g8) << 3;             // pre-swizzled src col (elems)

    const int b = bh >> 4, hh = bh & 15;
    unsigned short* op = (s == 2) ? op2 : op01 + (size_t)s * ((size_t)M_TOT * D_MODEL);

    auto stage = [&](int buf, int kv0s) {
        #pragma unroll
        for (int i = 0; i < 2; ++i) {
            const int cidx = w * 2 + i;          // 8 chunks of 8 rows
            const int row  = cidx * 8 + g8;
            __builtin_amdgcn_global_load_lds(
                (gvoid*)(kp + (size_t)(kv0s + row) * D_K + csrc),
                (lvoid*)&lK[buf][cidx * 512], 16, 0, 0);
            __builtin_amdgcn_global_load_lds(
                (gvoid*)(vp + (size_t)row * T_SEQ + kv0s + csrc),
                (lvoid*)&lV[buf][cidx * 512], 16, 0, 0);
        }
    };

    #pragma unroll 1
    for (int ci = 0; ci < 2; ++ci) {
        const int c   = ci ? p : (15 - p);       // heavy chunk first
        const int q0w = c * QCH + w * 32;
        const int cnt = (2 * c + 1 >= s) ? (2 * c + 1 - s) / 3 + 1 : 0;

        const unsigned short* qp = q + ((size_t)bh * T_SEQ + q0w) * D_K;
        short8 qf[2][2];
        #pragma unroll
        for (int qt = 0; qt < 2; ++qt)
            #pragma unroll
            for (int ks = 0; ks < 2; ++ks)
                qf[qt][ks] = *(const short8*)&qp[(qt * 16 + i16) * D_K + ks * 32 + g4 * 8];

        f32x4 o[2][4] = {};
        float l[2] = {0.f, 0.f};

        if (cnt > 0) stage(0, s * 64);
        __syncthreads();

        for (int it = 0; it < cnt; ++it) {
            const int cur = it & 1;
            const int kv0 = (s + 3 * it) * 64;
            if (it + 1 < cnt) stage(cur ^ 1, kv0 + 192);   // overlap with compute

            if (kv0 <= q0w + 31) {
                const bool act0 = (kv0 <= q0w + 15);
                const unsigned short* Kc = &lK[cur][0];
                const unsigned short* Vc = &lV[cur][0];

                // ---- S^T = K * Q^T ----
                f32x4 sA[4][2] = {};
                __builtin_amdgcn_s_setprio(1);
                #pragma unroll
                for (int ks = 0; ks < 2; ++ks)
                    #pragma unroll
                    for (int kt = 0; kt < 4; ++kt) {
                        short8 ka = *(const short8*)&Kc[(kt * 16 + i16) * 64 + ((ks * 32 + g4 * 8) ^ swz)];
                        if (act0)
                            sA[kt][0] = __builtin_amdgcn_mfma_f32_16x16x32_bf16(ka, qf[0][ks], sA[kt][0], 0, 0, 0);
                        sA[kt][1] = __builtin_amdgcn_mfma_f32_16x16x32_bf16(ka, qf[1][ks], sA[kt][1], 0, 0, 0);
                    }
                __builtin_amdgcn_s_setprio(0);

                // ---- softmax for BOTH q-tiles (independent chains overlap) ----
                #pragma unroll
                for (int qt = 0; qt < 2; ++qt) {
                    if (qt == 0 && !act0) continue;
                    const int qrow = q0w + qt * 16 + i16;
                    const bool diag = (kv0 + 63 > q0w + qt * 16);
                    float ps = 0.f;
                    unsigned pk[8];
                    #pragma unroll
                    for (int kt = 0; kt < 4; ++kt) {
                        f32x4 sc = sA[kt][qt];
                        if (diag) {
                            #pragma unroll
                            for (int r = 0; r < 4; ++r)
                                if (kv0 + kt * 16 + g4 * 4 + r > qrow) sc[r] = -3e38f;
                        }
                        float p0 = fexp2(sc[0]), p1 = fexp2(sc[1]);
                        float p2 = fexp2(sc[2]), p3 = fexp2(sc[3]);
                        ps += (p0 + p1) + (p2 + p3);
                        pk[kt * 2]     = cvt_pk_bf16(p0, p1);
                        pk[kt * 2 + 1] = cvt_pk_bf16(p2, p3);
                    }
                    l[qt] += ps;
                    unsigned short* Pw = &lP[w][qt][0];
                    #pragma unroll
                    for (int kt = 0; kt < 4; ++kt) {
                        uint2 v2; v2.x = pk[kt * 2]; v2.y = pk[kt * 2 + 1];
                        *(uint2*)&Pw[i16 * 64 + ((kt * 16 + g4 * 4) ^ swz)] = v2;
                    }
                }

                // ---- PV for BOTH q-tiles (one MFMA cluster) ----
                __builtin_amdgcn_s_setprio(1);
                #pragma unroll
                for (int qt = 0; qt < 2; ++qt) {
                    if (qt == 0 && !act0) continue;
                    const unsigned short* Pw = &lP[w][qt][0];
                    short8 pB0 = *(const short8*)&Pw[i16 * 64 + (( 0 + g4 * 8) ^ swz)];
                    short8 pB1 = *(const short8*)&Pw[i16 * 64 + ((32 + g4 * 8) ^ swz)];
                    #pragma unroll
                    for (int dt = 0; dt < 4; ++dt) {
                        short8 va0 = *(const short8*)&Vc[(dt * 16 + i16) * 64 + (( 0 + g4 * 8) ^ swz)];
                        short8 va1 = *(const short8*)&Vc[(dt * 16 + i16) * 64 + ((32 + g4 * 8) ^ swz)];
                        o[qt][dt] = __builtin_amdgcn_mfma_f32_16x16x32_bf16(va0, pB0, o[qt][dt], 0, 0, 0);
                        o[qt][dt] = __builtin_amdgcn_mfma_f32_16x16x32_bf16(va1, pB1, o[qt][dt], 0, 0, 0);
                    }
                }
                __builtin_amdgcn_s_setprio(0);
            }
            __syncthreads();   // next tile staged; cur buffer free
        }

        // ---- write this chunk's partials (unnormalized o + l) ----
        #pragma unroll
        for (int qt = 0; qt < 2; ++qt) {
            float lt = l[qt] + __shfl_xor(l[qt], 16);
            lt += __shfl_xor(lt, 32);
            const int trow = q0w + qt * 16 + i16;
            if (g4 == 0)
                lws[((size_t)s * 32 + bh) * T_SEQ + trow] = lt;
            #pragma unroll
            for (int dt = 0; dt < 4; ++dt) {
                u16x4 ov;
                ov.x = f2bf(o[qt][dt][0]);
                ov.y = f2bf(o[qt][dt][1]);
                ov.z = f2bf(o[qt][dt][2]);
                ov.w = f2bf(o[qt][dt][3]);
                *(u16x4*)&op[((size_t)(b * T_SEQ) + trow) * D_MODEL + hh * D_K + dt * 16 + g4 * 4] = ov;
            }
        }
        __syncthreads();       // LDS reuse safety before next phase's stage
    }
}

// ---------------- merge 3-way kv-split: y = (o0+o1+o2)/(l0+l1+l2) ----------------
__global__ __launch_bounds__(256) void merge3(const unsigned short* __restrict__ op01,
                                              const unsigned short* __restrict__ op2,
                                              const float* __restrict__ lws,
                                              unsigned short* __restrict__ y) {
    const int idx = blockIdx.x * 256 + threadIdx.x;
    const int gl  = idx * 8;
    const int row = gl >> 10;
    const int col = gl & 1023;
    const int b = row >> 11, t = row & (T_SEQ - 1), h = col >> 6;
    const int bh = b * 16 + h;
    const float l0 = lws[((size_t)bh) * T_SEQ + t];
    const float l1 = lws[((size_t)(32 + bh)) * T_SEQ + t];
    const float l2 = lws[((size_t)(64 + bh)) * T_SEQ + t];
    const float inv = 1.0f / (l0 + l1 + l2);
    short8 a0 = *(const short8*)&op01[gl];
    short8 a1 = *(const short8*)&op01[(size_t)M_TOT * D_MODEL + gl];
    short8 a2 = *(const short8*)&op2[gl];
    short8 r;
    #pragma unroll
    for (int j = 0; j < 8; ++j) {
        float f = bf2f((unsigned short)a0[j]) + bf2f((unsigned short)a1[j]) + bf2f((unsigned short)a2[j]);
        r[j] = (short)f2bf(f * inv);
    }
    *(short8*)&y[gl] = r;
}

extern "C" void kernel_launch(void* const* d_in, const int* in_sizes, int n_in,
                              void* d_out, int out_size, void* d_ws, size_t ws_size,
                              hipStream_t stream) {
    const float* x  = (const float*)d_in[0];
    const float* Wq = (const float*)d_in[1];
    const float* bq = (const float*)d_in[2];
    const float* Wk = (const float*)d_in[3];
    const float* bk = (const float*)d_in[4];
    const float* Wv = (const float*)d_in[5];
    const float* bv = (const float*)d_in[6];
    const float* Wo = (const float*)d_in[7];
    const float* bo = (const float*)d_in[8];

    uint8_t* ws = (uint8_t*)d_ws;
    const size_t MB = (size_t)1 << 20;
    unsigned short* xb  = (unsigned short*)(ws);              // 8 MiB; reused as o-partial s=2
    unsigned short* wqt = (unsigned short*)(ws + 8  * MB);    // 2 MiB (reused as lws)
    unsigned short* wkt = (unsigned short*)(ws + 10 * MB);
    unsigned short* wvt = (unsigned short*)(ws + 12 * MB);
    unsigned short* wot = (unsigned short*)(ws + 14 * MB);
    unsigned short* qb  = (unsigned short*)(ws + 16 * MB);    // 8 MiB; reused as y after flash
    unsigned short* kb  = (unsigned short*)(ws + 24 * MB);
    unsigned short* vtb = (unsigned short*)(ws + 32 * MB);
    float* lws = (float*)(ws + 8 * MB);   // 768 KB; wqt dead after gemm_qkv

    cvt_all<<<dim3(32, 32, 5), dim3(32, 8), 0, stream>>>(x, xb, Wq, Wk, Wv, Wo, wqt, wkt, wvt, wot);

    gemm_qkv<<<dim3(8, 32, 3), 256, 0, stream>>>(xb, wqt, wkt, wvt, bq, bk, bv, qb, kb, vtb);

    // partials: s=0,1 in d_out (2 x 8 MB), s=2 in xb (x dead); merged y -> qb (q dead)
    flash7<<<768, 256, 0, stream>>>(qb, kb, vtb, (unsigned short*)d_out, xb, lws);
    merge3<<<2048, 256, 0, stream>>>((const unsigned short*)d_out, xb, lws, qb);

    gemm_out<<<dim3(16, 32), 256, 0, stream>>>(qb, wot, bo, (float*)d_out);
}

// Round 17
// 114.573 us; speedup vs baseline: 1.0267x; 1.0267x over previous
//
#include <hip/hip_runtime.h>
#include <stdint.h>

#define D_MODEL 1024
#define N_HEADS 16
#define D_K     64
#define T_SEQ   2048
#define BATCH   2
#define M_TOT   (BATCH * T_SEQ)   // 4096
#define QCH     128               // q rows per chunk (16 chunks per bh)

typedef __attribute__((ext_vector_type(8))) short  short8;
typedef __attribute__((ext_vector_type(4))) float  f32x4;
typedef __attribute__((ext_vector_type(4))) unsigned short u16x4;

typedef __attribute__((address_space(1))) void gvoid;
typedef __attribute__((address_space(3))) void lvoid;

// log2(e)/8 : folds the 1/sqrt(Dk) scale AND the exp->exp2 conversion into Q
#define QSCALE 0.18033688011112042f

static __device__ __forceinline__ unsigned short f2bf(float f) {
    union { float f; unsigned u; } v; v.f = f;
    unsigned u = v.u;
    u += 0x7fffu + ((u >> 16) & 1u);   // RNE
    return (unsigned short)(u >> 16);
}
static __device__ __forceinline__ float bf2f(unsigned short s) {
    union { unsigned u; float f; } v; v.u = ((unsigned)s) << 16;
    return v.f;
}
static __device__ __forceinline__ float fexp2(float x) {
    float r;
    asm("v_exp_f32 %0, %1" : "=v"(r) : "v"(x));
    return r;
}
static __device__ __forceinline__ unsigned cvt_pk_bf16(float lo, float hi) {
    unsigned r;
    asm("v_cvt_pk_bf16_f32 %0, %1, %2" : "=v"(r) : "v"(lo), "v"(hi));
    return r;
}

// ------- fused converter (proven R11-R15): z=0 -> x fp32->bf16,
// z=1..4 -> W fp32 [K][N] -> bf16 [N][K] transpose -------
__global__ void cvt_all(const float* __restrict__ x, unsigned short* __restrict__ xo,
                        const float* w0, const float* w1, const float* w2, const float* w3,
                        unsigned short* o0, unsigned short* o1, unsigned short* o2, unsigned short* o3) {
    if (blockIdx.z == 0) {
        const int tid = threadIdx.y * 32 + threadIdx.x;
        const int bid = blockIdx.y * 32 + blockIdx.x;          // 0..1023
        const float4* in4 = (const float4*)x;
        #pragma unroll
        for (int j = 0; j < 4; ++j) {
            int i = bid * 256 + tid + j * 262144;
            float4 v = in4[i];
            u16x4 o;
            o.x = f2bf(v.x); o.y = f2bf(v.y); o.z = f2bf(v.z); o.w = f2bf(v.w);
            *(u16x4*)&xo[(size_t)i * 4] = o;
        }
        return;
    }
    const float* w; unsigned short* o;
    switch (blockIdx.z - 1) {
        case 0: w = w0; o = o0; break;
        case 1: w = w1; o = o1; break;
        case 2: w = w2; o = o2; break;
        default: w = w3; o = o3; break;
    }
    __shared__ float tile[32][33];
    int n0 = blockIdx.x * 32, k0 = blockIdx.y * 32;
    int tx = threadIdx.x, ty = threadIdx.y;              // 32 x 8
    #pragma unroll
    for (int r = 0; r < 32; r += 8)
        tile[ty + r][tx] = w[(size_t)(k0 + ty + r) * D_MODEL + n0 + tx];
    __syncthreads();
    #pragma unroll
    for (int r = 0; r < 32; r += 8)
        o[(size_t)(n0 + ty + r) * D_MODEL + k0 + tx] = f2bf(tile[tx][ty + r]);
}

// ---------------- fused QKV 128x128-tile bf16 GEMM -- BYTE-EXACT R9/R13/R15 ----------
// dim3(8,32,3); BK=32 / 16KB LDS, 2-phase. FROZEN: BK=64 (R7), grid remap (R5),
// LDS swizzle (R7), uint2 z2 epilogue (R10-R12), 3-buf counted vmcnt (R16:
// 43.2->45.7us, reproduces m131/m218 regime-gate) ALL regressed.
__global__ __launch_bounds__(256) void gemm_qkv(const unsigned short* __restrict__ A,
                                                const unsigned short* __restrict__ wq,
                                                const unsigned short* __restrict__ wk,
                                                const unsigned short* __restrict__ wv,
                                                const float* __restrict__ bq,
                                                const float* __restrict__ bk,
                                                const float* __restrict__ bv,
                                                unsigned short* __restrict__ qo,
                                                unsigned short* __restrict__ ko,
                                                unsigned short* __restrict__ vo) {
    const int z = blockIdx.z;
    const unsigned short* Bt = (z == 0) ? wq : (z == 1) ? wk : wv;
    const float* bias = (z == 0) ? bq : (z == 1) ? bk : bv;
    const float alpha = (z == 0) ? QSCALE : 1.0f;

    __shared__ unsigned short lA[128 * 32];
    __shared__ unsigned short lB[128 * 32];
    const int tid  = threadIdx.x;
    const int w    = tid >> 6, lane = tid & 63;
    const int tm   = blockIdx.y, tn = blockIdx.x;
    const int wm   = w & 1, wn = w >> 1;
    const int i16  = lane & 15, g4 = lane >> 4;
    f32x4 acc[4][4] = {};

    const int rA0 = tm * 128, rB0 = tn * 128;
    const int srow = lane >> 2;
    const int skc  = (lane & 3) * 8;

    for (int k0 = 0; k0 < D_MODEL; k0 += 32) {
        #pragma unroll
        for (int is = 0; is < 2; ++is) {
            int c   = is * 4 + w;
            int row = c * 16 + srow;
            __builtin_amdgcn_global_load_lds(
                (gvoid*)(A + (size_t)(rA0 + row) * D_MODEL + k0 + skc),
                (lvoid*)&lA[c * 512], 16, 0, 0);
            __builtin_amdgcn_global_load_lds(
                (gvoid*)(Bt + (size_t)(rB0 + row) * D_MODEL + k0 + skc),
                (lvoid*)&lB[c * 512], 16, 0, 0);
        }
        __syncthreads();
        short8 af[4], bfr[4];
        #pragma unroll
        for (int mi = 0; mi < 4; ++mi)
            af[mi] = *(const short8*)&lA[(wm * 64 + mi * 16 + i16) * 32 + g4 * 8];
        #pragma unroll
        for (int ni = 0; ni < 4; ++ni)
            bfr[ni] = *(const short8*)&lB[(wn * 64 + ni * 16 + i16) * 32 + g4 * 8];
        #pragma unroll
        for (int mi = 0; mi < 4; ++mi)
            #pragma unroll
            for (int ni = 0; ni < 4; ++ni)
                acc[mi][ni] = __builtin_amdgcn_mfma_f32_16x16x32_bf16(af[mi], bfr[ni], acc[mi][ni], 0, 0, 0);
        __syncthreads();
    }

    #pragma unroll
    for (int mi = 0; mi < 4; ++mi)
        #pragma unroll
        for (int ni = 0; ni < 4; ++ni) {
            int col = tn * 128 + wn * 64 + ni * 16 + i16;
            float bv2 = bias[col];
            #pragma unroll
            for (int r = 0; r < 4; ++r) {
                int row = tm * 128 + wm * 64 + mi * 16 + g4 * 4 + r;
                float val = (acc[mi][ni][r] + bv2) * alpha;
                int b = row >> 11, t = row & (T_SEQ - 1);
                int h = col >> 6,  d = col & (D_K - 1);
                unsigned short bfv = f2bf(val);
                if (z == 2)
                    vo[(((size_t)(b * N_HEADS + h)) * D_K + d) * T_SEQ + t] = bfv;
                else if (z == 1)
                    ko[(((size_t)(b * N_HEADS + h)) * T_SEQ + t) * D_K + d] = bfv;
                else
                    qo[(((size_t)(b * N_HEADS + h)) * T_SEQ + t) * D_K + d] = bfv;
            }
        }
}

// ---------------- output-projection GEMM (fp32 out + bias), 128x64 tiles ----------
// Proven R14/R15: dim3(16,32) = 512 blocks = 2/CU.
__global__ __launch_bounds__(256) void gemm_out(const unsigned short* __restrict__ A,
                                                const unsigned short* __restrict__ Bt,
                                                const float* __restrict__ bias,
                                                float* __restrict__ Cout) {
    __shared__ unsigned short lA[128 * 32];   // 8 KB
    __shared__ unsigned short lB[64 * 32];    // 4 KB
    const int tid  = threadIdx.x;
    const int w    = tid >> 6, lane = tid & 63;
    const int tm   = blockIdx.y, tn = blockIdx.x;      // tn: 0..15 (64-wide)
    const int wm   = w & 1, wn = w >> 1;               // wn: 0..1 (32-wide)
    const int i16  = lane & 15, g4 = lane >> 4;
    f32x4 acc[4][2] = {};

    const int rA0 = tm * 128, rB0 = tn * 64;
    const int srow = lane >> 2;
    const int skc  = (lane & 3) * 8;

    for (int k0 = 0; k0 < D_MODEL; k0 += 32) {
        #pragma unroll
        for (int is = 0; is < 2; ++is) {
            int c   = is * 4 + w;                      // A: 8 chunks of 16 rows
            int row = c * 16 + srow;
            __builtin_amdgcn_global_load_lds(
                (gvoid*)(A + (size_t)(rA0 + row) * D_MODEL + k0 + skc),
                (lvoid*)&lA[c * 512], 16, 0, 0);
        }
        {
            int row = w * 16 + srow;                   // B: 4 chunks of 16 rows
            __builtin_amdgcn_global_load_lds(
                (gvoid*)(Bt + (size_t)(rB0 + row) * D_MODEL + k0 + skc),
                (lvoid*)&lB[w * 512], 16, 0, 0);
        }
        __syncthreads();
        short8 af[4], bfr[2];
        #pragma unroll
        for (int mi = 0; mi < 4; ++mi)
            af[mi] = *(const short8*)&lA[(wm * 64 + mi * 16 + i16) * 32 + g4 * 8];
        #pragma unroll
        for (int ni = 0; ni < 2; ++ni)
            bfr[ni] = *(const short8*)&lB[(wn * 32 + ni * 16 + i16) * 32 + g4 * 8];
        #pragma unroll
        for (int mi = 0; mi < 4; ++mi)
            #pragma unroll
            for (int ni = 0; ni < 2; ++ni)
                acc[mi][ni] = __builtin_amdgcn_mfma_f32_16x16x32_bf16(af[mi], bfr[ni], acc[mi][ni], 0, 0, 0);
        __syncthreads();
    }

    #pragma unroll
    for (int mi = 0; mi < 4; ++mi)
        #pragma unroll
        for (int ni = 0; ni < 2; ++ni) {
            int col = tn * 64 + wn * 32 + ni * 16 + i16;
            float bv2 = bias[col];
            #pragma unroll
            for (int r = 0; r < 4; ++r) {
                int row = tm * 128 + wm * 64 + mi * 16 + g4 * 4 + r;
                Cout[(size_t)row * D_MODEL + col] = acc[mi][ni][r] + bv2;
            }
        }
}

// ---------------- causal flash attention v9: un-paired + 40KB LDS -> 4 blocks/CU ----
// R14's un-pairing failed because lP[4][2][...] kept LDS at 48KB (occ stayed 17%).
// v9 uses flash6's proven single-qt P slab (8KB; flash6 ~= flash7 perf) so LDS
// = 16+16+8 = 40KB -> TRUE 4 blocks/CU with 1536 blocks. 16 waves/CU resident
// + 6 assigned blocks/CU of backfill. Inner math identical to flash6 (R6).
__global__ __launch_bounds__(256, 4) void flash9(const unsigned short* __restrict__ q,
                                                 const unsigned short* __restrict__ k,
                                                 const unsigned short* __restrict__ vt,
                                                 unsigned short* __restrict__ op01,
                                                 unsigned short* __restrict__ op2,
                                                 float* __restrict__ lws) {
    __shared__ unsigned short lK[2][64 * 64];    // 16 KB  [kv row][d]
    __shared__ unsigned short lV[2][64 * 64];    // 16 KB  [d][kv col]
    __shared__ unsigned short lP[4][16 * 64];    //  8 KB  per-wave P slab (single qt)
    const int tid  = threadIdx.x;
    const int w    = tid >> 6, lane = tid & 63;
    const int i16  = lane & 15, g4 = lane >> 4;
    const int l8   = lane & 7,  g8 = lane >> 3;
    const int nb   = blockIdx.x;                 // (15-c)*96 + bh*3 + s
    const int c    = 15 - (nb / 96);             // heavy chunks first
    const int rem  = nb % 96;
    const int bh   = rem / 3;
    const int s    = rem % 3;

    const unsigned short* kp = k  + (size_t)bh * T_SEQ * D_K;
    const unsigned short* vp = vt + (size_t)bh * D_K * T_SEQ;
    unsigned short* Pw = &lP[w][0];
    const int swz  = (i16 & 7) << 3;             // XOR swizzle (element units)
    const int csrc = (l8 ^ g8) << 3;             // pre-swizzled src col (elems)

    const int b = bh >> 4, hh = bh & 15;
    unsigned short* op = (s == 2) ? op2 : op01 + (size_t)s * ((size_t)M_TOT * D_MODEL);

    auto stage = [&](int buf, int kv0s) {
        #pragma unroll
        for (int i = 0; i < 2; ++i) {
            const int cidx = w * 2 + i;          // 8 chunks of 8 rows
            const int row  = cidx * 8 + g8;
            __builtin_amdgcn_global_load_lds(
                (gvoid*)(kp + (size_t)(kv0s + row) * D_K + csrc),
                (lvoid*)&lK[buf][cidx * 512], 16, 0, 0);
            __builtin_amdgcn_global_load_lds(
                (gvoid*)(vp + (size_t)row * T_SEQ + kv0s + csrc),
                (lvoid*)&lV[buf][cidx * 512], 16, 0, 0);
        }
    };

    const int q0w = c * QCH + w * 32;
    const int cnt = (2 * c + 1 >= s) ? (2 * c + 1 - s) / 3 + 1 : 0;

    const unsigned short* qp = q + ((size_t)bh * T_SEQ + q0w) * D_K;
    short8 qf[2][2];
    #pragma unroll
    for (int qt = 0; qt < 2; ++qt)
        #pragma unroll
        for (int ks = 0; ks < 2; ++ks)
            qf[qt][ks] = *(const short8*)&qp[(qt * 16 + i16) * D_K + ks * 32 + g4 * 8];

    f32x4 o[2][4] = {};
    float l[2] = {0.f, 0.f};

    if (cnt > 0) stage(0, s * 64);
    __syncthreads();

    for (int it = 0; it < cnt; ++it) {
        const int cur = it & 1;
        const int kv0 = (s + 3 * it) * 64;
        if (it + 1 < cnt) stage(cur ^ 1, kv0 + 192);   // overlap with compute

        if (kv0 <= q0w + 31) {
            const bool act0 = (kv0 <= q0w + 15);
            const unsigned short* Kc = &lK[cur][0];
            const unsigned short* Vc = &lV[cur][0];

            // ---- S^T = K * Q^T ----
            f32x4 sA[4][2] = {};
            __builtin_amdgcn_s_setprio(1);
            #pragma unroll
            for (int ks = 0; ks < 2; ++ks)
                #pragma unroll
                for (int kt = 0; kt < 4; ++kt) {
                    short8 ka = *(const short8*)&Kc[(kt * 16 + i16) * 64 + ((ks * 32 + g4 * 8) ^ swz)];
                    if (act0)
                        sA[kt][0] = __builtin_amdgcn_mfma_f32_16x16x32_bf16(ka, qf[0][ks], sA[kt][0], 0, 0, 0);
                    sA[kt][1] = __builtin_amdgcn_mfma_f32_16x16x32_bf16(ka, qf[1][ks], sA[kt][1], 0, 0, 0);
                }
            __builtin_amdgcn_s_setprio(0);

            // ---- per-qt: softmax -> P slab -> PV (flash6-proven interleave) ----
            #pragma unroll
            for (int qt = 0; qt < 2; ++qt) {
                if (qt == 0 && !act0) continue;
                const int qrow = q0w + qt * 16 + i16;
                const bool diag = (kv0 + 63 > q0w + qt * 16);
                float ps = 0.f;
                unsigned pk[8];
                #pragma unroll
                for (int kt = 0; kt < 4; ++kt) {
                    f32x4 sc = sA[kt][qt];
                    if (diag) {
                        #pragma unroll
                        for (int r = 0; r < 4; ++r)
                            if (kv0 + kt * 16 + g4 * 4 + r > qrow) sc[r] = -3e38f;
                    }
                    float p0 = fexp2(sc[0]), p1 = fexp2(sc[1]);
                    float p2 = fexp2(sc[2]), p3 = fexp2(sc[3]);
                    ps += (p0 + p1) + (p2 + p3);
                    pk[kt * 2]     = cvt_pk_bf16(p0, p1);
                    pk[kt * 2 + 1] = cvt_pk_bf16(p2, p3);
                }
                l[qt] += ps;
                #pragma unroll
                for (int kt = 0; kt < 4; ++kt) {
                    uint2 v2; v2.x = pk[kt * 2]; v2.y = pk[kt * 2 + 1];
                    *(uint2*)&Pw[i16 * 64 + ((kt * 16 + g4 * 4) ^ swz)] = v2;
                }
                short8 pB0 = *(const short8*)&Pw[i16 * 64 + (( 0 + g4 * 8) ^ swz)];
                short8 pB1 = *(const short8*)&Pw[i16 * 64 + ((32 + g4 * 8) ^ swz)];
                __builtin_amdgcn_s_setprio(1);
                #pragma unroll
                for (int dt = 0; dt < 4; ++dt) {
                    short8 va0 = *(const short8*)&Vc[(dt * 16 + i16) * 64 + (( 0 + g4 * 8) ^ swz)];
                    short8 va1 = *(const short8*)&Vc[(dt * 16 + i16) * 64 + ((32 + g4 * 8) ^ swz)];
                    o[qt][dt] = __builtin_amdgcn_mfma_f32_16x16x32_bf16(va0, pB0, o[qt][dt], 0, 0, 0);
                    o[qt][dt] = __builtin_amdgcn_mfma_f32_16x16x32_bf16(va1, pB1, o[qt][dt], 0, 0, 0);
                }
                __builtin_amdgcn_s_setprio(0);
            }
        }
        __syncthreads();   // next tile staged; cur buffer free
    }

    // ---- write this chunk's partials (unnormalized o + l) ----
    #pragma unroll
    for (int qt = 0; qt < 2; ++qt) {
        float lt = l[qt] + __shfl_xor(l[qt], 16);
        lt += __shfl_xor(lt, 32);
        const int trow = q0w + qt * 16 + i16;
        if (g4 == 0)
            lws[((size_t)s * 32 + bh) * T_SEQ + trow] = lt;
        #pragma unroll
        for (int dt = 0; dt < 4; ++dt) {
            u16x4 ov;
            ov.x = f2bf(o[qt][dt][0]);
            ov.y = f2bf(o[qt][dt][1]);
            ov.z = f2bf(o[qt][dt][2]);
            ov.w = f2bf(o[qt][dt][3]);
            *(u16x4*)&op[((size_t)(b * T_SEQ) + trow) * D_MODEL + hh * D_K + dt * 16 + g4 * 4] = ov;
        }
    }
}

// ---------------- merge 3-way kv-split: y = (o0+o1+o2)/(l0+l1+l2) ----------------
__global__ __launch_bounds__(256) void merge3(const unsigned short* __restrict__ op01,
                                              const unsigned short* __restrict__ op2,
                                              const float* __restrict__ lws,
                                              unsigned short* __restrict__ y) {
    const int idx = blockIdx.x * 256 + threadIdx.x;
    const int gl  = idx * 8;
    const int row = gl >> 10;
    const int col = gl & 1023;
    const int b = row >> 11, t = row & (T_SEQ - 1), h = col >> 6;
    const int bh = b * 16 + h;
    const float l0 = lws[((size_t)bh) * T_SEQ + t];
    const float l1 = lws[((size_t)(32 + bh)) * T_SEQ + t];
    const float l2 = lws[((size_t)(64 + bh)) * T_SEQ + t];
    const float inv = 1.0f / (l0 + l1 + l2);
    short8 a0 = *(const short8*)&op01[gl];
    short8 a1 = *(const short8*)&op01[(size_t)M_TOT * D_MODEL + gl];
    short8 a2 = *(const short8*)&op2[gl];
    short8 r;
    #pragma unroll
    for (int j = 0; j < 8; ++j) {
        float f = bf2f((unsigned short)a0[j]) + bf2f((unsigned short)a1[j]) + bf2f((unsigned short)a2[j]);
        r[j] = (short)f2bf(f * inv);
    }
    *(short8*)&y[gl] = r;
}

extern "C" void kernel_launch(void* const* d_in, const int* in_sizes, int n_in,
                              void* d_out, int out_size, void* d_ws, size_t ws_size,
                              hipStream_t stream) {
    const float* x  = (const float*)d_in[0];
    const float* Wq = (const float*)d_in[1];
    const float* bq = (const float*)d_in[2];
    const float* Wk = (const float*)d_in[3];
    const float* bk = (const float*)d_in[4];
    const float* Wv = (const float*)d_in[5];
    const float* bv = (const float*)d_in[6];
    const float* Wo = (const float*)d_in[7];
    const float* bo = (const float*)d_in[8];

    uint8_t* ws = (uint8_t*)d_ws;
    const size_t MB = (size_t)1 << 20;
    unsigned short* xb  = (unsigned short*)(ws);              // 8 MiB; reused as o-partial s=2
    unsigned short* wqt = (unsigned short*)(ws + 8  * MB);    // 2 MiB (reused as lws)
    unsigned short* wkt = (unsigned short*)(ws + 10 * MB);
    unsigned short* wvt = (unsigned short*)(ws + 12 * MB);
    unsigned short* wot = (unsigned short*)(ws + 14 * MB);
    unsigned short* qb  = (unsigned short*)(ws + 16 * MB);    // 8 MiB; reused as y after flash
    unsigned short* kb  = (unsigned short*)(ws + 24 * MB);
    unsigned short* vtb = (unsigned short*)(ws + 32 * MB);
    float* lws = (float*)(ws + 8 * MB);   // 768 KB; wqt dead after gemm_qkv

    cvt_all<<<dim3(32, 32, 5), dim3(32, 8), 0, stream>>>(x, xb, Wq, Wk, Wv, Wo, wqt, wkt, wvt, wot);

    gemm_qkv<<<dim3(8, 32, 3), 256, 0, stream>>>(xb, wqt, wkt, wvt, bq, bk, bv, qb, kb, vtb);

    // partials: s=0,1 in d_out (2 x 8 MB), s=2 in xb (x dead); merged y -> qb (q dead)
    flash9<<<1536, 256, 0, stream>>>(qb, kb, vtb, (unsigned short*)d_out, xb, lws);
    merge3<<<2048, 256, 0, stream>>>((const unsigned short*)d_out, xb, lws, qb);

    gemm_out<<<dim3(16, 32), 256, 0, stream>>>(qb, wot, bo, (float*)d_out);
}